// Round 7
// baseline (150.485 us; speedup 1.0000x reference)
//
#include <hip/hip_runtime.h>
#include <math.h>

// monotonic_binary_output: out[r] = (u[r] < sigmoid-thresh[r]).
//
// v7: fully 16B-aligned load scheme via per-row static phase shift.
//  - quad = 4 rows = 2064 B, always 16B-aligned (2064 % 16 == 0).
//  - row i (i = r mod 4) is loaded with a phase shift p_i = (4-i)&3 floats:
//    (r*516 + 4*p_i) % 16 == 0, so every float4 segment is aligned, and the
//    shifted window [p, p+127] never leaves the quad (row 3 ends exactly at
//    the quad's last float). Cols >127 picked up by the shift get
//    compile-time zero weights.
//  - missing head cols 0..p-1 of rows 1..3 live in three aligned float4s at
//    quad float-offsets 128/256/384, loaded by lane 0 only; those blocks
//    (plus lane 15's row-3 segB) also contain all four z values -> the four
//    uniform z-loads are eliminated (shuffle-broadcast instead).
//  - all weight indices are compile-time (static p_i per unrolled i).
//  - numerics: f32 hot path + rare f64 escape (re-reads x from global),
//    decisions identical to the pure-f64 kernel (absmax == 0.0, R1-R6).

constexpr int LATENT = 128;
constexpr int RS     = 129;          // x row stride in floats
constexpr int QF     = 4 * RS;       // 516 floats = 2064 B per quad
constexpr int LPR    = 16;           // lanes per row
constexpr int ROWS   = 4;            // rows per group-iteration (one quad)

__device__ __forceinline__ float elem(const float4& v, int e) {
    return reinterpret_cast<const float*>(&v)[e];   // e is compile-time
}

__global__ __launch_bounds__(256, 4)
void mono_kernel(const float* __restrict__ x,
                 const float* __restrict__ W,
                 const float* __restrict__ b,
                 const float* __restrict__ u,
                 float* __restrict__ out,
                 int N)
{
    const int tid   = blockIdx.x * blockDim.x + threadIdx.x;
    const int sub   = threadIdx.x & (LPR - 1);
    const int wl    = threadIdx.x & 63;
    const int gbase = wl & 48;                 // group's base wave-lane
    const int grp   = tid >> 4;
    const int ngrp  = (gridDim.x * blockDim.x) >> 4;

    // segA weights: cols 4s..4s+6 ; segB: cols 64+4s..64+4s+6 (0 past 127).
    float wA0[7], wA1[7], wB0[7], wB1[7];
#pragma unroll
    for (int d = 0; d < 7; ++d) {
        const int ca = 4 * sub + d;
        wA0[d] = W[2 * ca + 0];
        wA1[d] = W[2 * ca + 1];
        const int cb = 64 + 4 * sub + d;
        const bool ok = cb < 128;
        wB0[d] = ok ? W[2 * cb + 0] : 0.0f;
        wB1[d] = ok ? W[2 * cb + 1] : 0.0f;
    }
    // head weights: cols 0..2 (used by lane 0 only).
    float wh0[3], wh1[3];
#pragma unroll
    for (int e = 0; e < 3; ++e) { wh0[e] = W[2 * e]; wh1[e] = W[2 * e + 1]; }
    const float b0f = b[0];
    const float b1f = b[1];

    const int nquad = N >> 2;                  // N = 1e6, divisible by 4
    for (int g = grp; g < nquad; g += ngrp) {
        const int r0 = 4 * g;
        const float* q = x + (size_t)g * QF;   // 16B-aligned quad base

        // ---- aligned segment loads (all float4s 16B-aligned) ----
        float4 va[ROWS], vb[ROWS];
#pragma unroll
        for (int i = 0; i < ROWS; ++i) {
            const int p = (4 - i) & 3;         // static per unrolled i
            const float* rbase = q + RS * i + p;
            va[i] = *reinterpret_cast<const float4*>(rbase + 4 * sub);
            vb[i] = *reinterpret_cast<const float4*>(rbase + 64 + 4 * sub);
        }

        // ---- head blocks (lane 0 of each group): quad floats 128/256/384 ----
        float4 h1, h2, h3;
        float z0 = 0.0f, z1 = 0.0f, z2 = 0.0f;
        if (sub == 0) {
            h1 = *reinterpret_cast<const float4*>(q + 128);  // z0, row1 c0..2
            h2 = *reinterpret_cast<const float4*>(q + 256);  // _, z1, row2 c0..1
            h3 = *reinterpret_cast<const float4*>(q + 384);  // _, _, z2, row3 c0
            z0 = h1.x; z1 = h2.y; z2 = h3.z;
        }
        const float4 uv = *reinterpret_cast<const float4*>(u + r0);
        const float uu[ROWS] = {uv.x, uv.y, uv.z, uv.w};

        // ---- f32 dot, static phase-shifted weight indexing ----
        float s0[ROWS], s1[ROWS];
#pragma unroll
        for (int i = 0; i < ROWS; ++i) {
            const int p = (4 - i) & 3;
            float a0 = 0.0f, a1 = 0.0f;
#pragma unroll
            for (int e = 0; e < 4; ++e) {
                const float fe = elem(va[i], e);   // col p+4s+e
                a0 = fmaf(fe, wA0[p + e], a0);
                a1 = fmaf(fe, wA1[p + e], a1);
                const float ge = elem(vb[i], e);   // col 64+p+4s+e
                a0 = fmaf(ge, wB0[p + e], a0);
                a1 = fmaf(ge, wB1[p + e], a1);
            }
            s0[i] = a0; s1[i] = a1;
        }
        // lane 0 adds the missing head cols of rows 1..3.
        if (sub == 0) {
            s0[1] = fmaf(h1.y, wh0[0], fmaf(h1.z, wh0[1], fmaf(h1.w, wh0[2], s0[1])));
            s1[1] = fmaf(h1.y, wh1[0], fmaf(h1.z, wh1[1], fmaf(h1.w, wh1[2], s1[1])));
            s0[2] = fmaf(h2.z, wh0[0], fmaf(h2.w, wh0[1], s0[2]));
            s1[2] = fmaf(h2.z, wh1[0], fmaf(h2.w, wh1[1], s1[2]));
            s0[3] = fmaf(h3.w, wh0[0], s0[3]);
            s1[3] = fmaf(h3.w, wh1[0], s1[3]);
        }

        // ---- butterfly reduce within the 16-lane group ----
#pragma unroll
        for (int m = 8; m >= 1; m >>= 1) {
#pragma unroll
            for (int i = 0; i < ROWS; ++i) {
                s0[i] += __shfl_xor(s0[i], m, 64);
                s1[i] += __shfl_xor(s1[i], m, 64);
            }
        }

        // ---- z broadcast (z0..z2 from lane 0's heads, z3 from lane 15 segB) ----
        float zz[ROWS];
        zz[0] = __shfl(z0, gbase, 64);
        zz[1] = __shfl(z1, gbase, 64);
        zz[2] = __shfl(z2, gbase, 64);
        zz[3] = __shfl(vb[3].w, gbase + 15, 64);   // row3 p=1: segB e3 = col 128

        // ---- f32 decision with conservative escalation test ----
        float oo[ROWS];
        bool esc = false;
#pragma unroll
        for (int i = 0; i < ROWS; ++i) {
            const float l0 = s0[i] + b0f;
            const float l1 = s1[i] + b1f;
            const float t  = (zz[i] == 1.0f) ? fmaxf(l0, l1) : fminf(l0, l1);
            const float qd = uu[i] * (1.0f + expf(-t));
            oo[i] = (qd < 1.0f) ? 1.0f : 0.0f;
            esc = esc || (fabsf(qd - 1.0f) < 2.5e-4f * (1.0f + qd));
        }

        // ---- rare exact f64 recompute (group-uniform branch; reloads x) ----
        if (__builtin_expect(esc, 0)) {
#pragma unroll 1
            for (int i = 0; i < ROWS; ++i) {
                const float* xr = x + (size_t)(r0 + i) * RS;
                double d0 = 0.0, d1 = 0.0;
#pragma unroll
                for (int j = 0; j < 8; ++j) {
                    const int c = 4 * sub + (j & 3) + 64 * (j >> 2);
                    const double xv = (double)xr[c];
                    d0 = fma(xv, (double)W[2 * c + 0], d0);
                    d1 = fma(xv, (double)W[2 * c + 1], d1);
                }
#pragma unroll
                for (int m = 8; m >= 1; m >>= 1) {
                    d0 += __shfl_xor(d0, m, 64);
                    d1 += __shfl_xor(d1, m, 64);
                }
                const double l0 = d0 + (double)b0f;
                const double l1 = d1 + (double)b1f;
                const double t  = (zz[i] == 1.0f) ? fmax(l0, l1) : fmin(l0, l1);
                oo[i] = ((double)uu[i] * (1.0 + exp(-t)) < 1.0) ? 1.0f : 0.0f;
            }
        }

        if (sub == 0) {
            *reinterpret_cast<float4*>(out + r0) =
                make_float4(oo[0], oo[1], oo[2], oo[3]);
        }
    }
}

extern "C" void kernel_launch(void* const* d_in, const int* in_sizes, int n_in,
                              void* d_out, int out_size, void* d_ws, size_t ws_size,
                              hipStream_t stream) {
    const float* x = (const float*)d_in[0];
    const float* W = (const float*)d_in[1];
    const float* b = (const float*)d_in[2];
    const float* u = (const float*)d_in[3];
    float* out = (float*)d_out;
    const int N = in_sizes[3];   // u has N elements

    const int blocks = 4096;     // grid-stride; 256 thr = 16 groups/block
    mono_kernel<<<blocks, 256, 0, stream>>>(x, W, b, u, out, N);
}

// Round 8
// 103.225 us; speedup vs baseline: 1.4578x; 1.4578x over previous
//
#include <hip/hip_runtime.h>
#include <math.h>

// monotonic_binary_output: out[r] = (u[r] < sigmoid-thresh[r]).
//
// v8 = v7 with ONE change: __launch_bounds__(256,2) instead of (256,4).
// R7's 150us regression is attributed to the 128-VGPR cap forcing spill
// (same signature as R1: 243us -> 110us when the cap was lifted). This is
// the minimal diff isolating the alignment scheme from the register cap.
//
//  - quad = 4 rows = 2064 B, always 16B-aligned (2064 % 16 == 0).
//  - row i loaded with static phase p_i = (4-i)&3 floats -> every float4
//    segment 16B-aligned; shifted window never leaves the quad.
//  - missing head cols of rows 1..3 come from three aligned float4s
//    (lane 0), which also carry z0..z2; z3 comes from lane 15's segB.
//  - numerics: f32 hot path + rare f64 escape (re-reads x from global),
//    decisions identical to the pure-f64 kernel (absmax == 0.0, R1-R7).

constexpr int LATENT = 128;
constexpr int RS     = 129;          // x row stride in floats
constexpr int QF     = 4 * RS;       // 516 floats = 2064 B per quad
constexpr int LPR    = 16;           // lanes per row
constexpr int ROWS   = 4;            // rows per group-iteration (one quad)

__device__ __forceinline__ float elem(const float4& v, int e) {
    return reinterpret_cast<const float*>(&v)[e];   // e is compile-time
}

__global__ __launch_bounds__(256, 2)
void mono_kernel(const float* __restrict__ x,
                 const float* __restrict__ W,
                 const float* __restrict__ b,
                 const float* __restrict__ u,
                 float* __restrict__ out,
                 int N)
{
    const int tid   = blockIdx.x * blockDim.x + threadIdx.x;
    const int sub   = threadIdx.x & (LPR - 1);
    const int wl    = threadIdx.x & 63;
    const int gbase = wl & 48;                 // group's base wave-lane
    const int grp   = tid >> 4;
    const int ngrp  = (gridDim.x * blockDim.x) >> 4;

    // segA weights: cols 4s..4s+6 ; segB: cols 64+4s..64+4s+6 (0 past 127).
    float wA0[7], wA1[7], wB0[7], wB1[7];
#pragma unroll
    for (int d = 0; d < 7; ++d) {
        const int ca = 4 * sub + d;
        wA0[d] = W[2 * ca + 0];
        wA1[d] = W[2 * ca + 1];
        const int cb = 64 + 4 * sub + d;
        const bool ok = cb < 128;
        wB0[d] = ok ? W[2 * cb + 0] : 0.0f;
        wB1[d] = ok ? W[2 * cb + 1] : 0.0f;
    }
    // head weights: cols 0..2 (used by lane 0 only).
    float wh0[3], wh1[3];
#pragma unroll
    for (int e = 0; e < 3; ++e) { wh0[e] = W[2 * e]; wh1[e] = W[2 * e + 1]; }
    const float b0f = b[0];
    const float b1f = b[1];

    const int nquad = N >> 2;                  // N = 1e6, divisible by 4
    for (int g = grp; g < nquad; g += ngrp) {
        const int r0 = 4 * g;
        const float* q = x + (size_t)g * QF;   // 16B-aligned quad base

        // ---- aligned segment loads (all float4s 16B-aligned) ----
        float4 va[ROWS], vb[ROWS];
#pragma unroll
        for (int i = 0; i < ROWS; ++i) {
            const int p = (4 - i) & 3;         // static per unrolled i
            const float* rbase = q + RS * i + p;
            va[i] = *reinterpret_cast<const float4*>(rbase + 4 * sub);
            vb[i] = *reinterpret_cast<const float4*>(rbase + 64 + 4 * sub);
        }

        // ---- head blocks (lane 0 of each group): quad floats 128/256/384 ----
        float4 h1, h2, h3;
        float z0 = 0.0f, z1 = 0.0f, z2 = 0.0f;
        if (sub == 0) {
            h1 = *reinterpret_cast<const float4*>(q + 128);  // z0, row1 c0..2
            h2 = *reinterpret_cast<const float4*>(q + 256);  // _, z1, row2 c0..1
            h3 = *reinterpret_cast<const float4*>(q + 384);  // _, _, z2, row3 c0
            z0 = h1.x; z1 = h2.y; z2 = h3.z;
        }
        const float4 uv = *reinterpret_cast<const float4*>(u + r0);
        const float uu[ROWS] = {uv.x, uv.y, uv.z, uv.w};

        // ---- f32 dot, static phase-shifted weight indexing ----
        float s0[ROWS], s1[ROWS];
#pragma unroll
        for (int i = 0; i < ROWS; ++i) {
            const int p = (4 - i) & 3;
            float a0 = 0.0f, a1 = 0.0f;
#pragma unroll
            for (int e = 0; e < 4; ++e) {
                const float fe = elem(va[i], e);   // col p+4s+e
                a0 = fmaf(fe, wA0[p + e], a0);
                a1 = fmaf(fe, wA1[p + e], a1);
                const float ge = elem(vb[i], e);   // col 64+p+4s+e
                a0 = fmaf(ge, wB0[p + e], a0);
                a1 = fmaf(ge, wB1[p + e], a1);
            }
            s0[i] = a0; s1[i] = a1;
        }
        // lane 0 adds the missing head cols of rows 1..3.
        if (sub == 0) {
            s0[1] = fmaf(h1.y, wh0[0], fmaf(h1.z, wh0[1], fmaf(h1.w, wh0[2], s0[1])));
            s1[1] = fmaf(h1.y, wh1[0], fmaf(h1.z, wh1[1], fmaf(h1.w, wh1[2], s1[1])));
            s0[2] = fmaf(h2.z, wh0[0], fmaf(h2.w, wh0[1], s0[2]));
            s1[2] = fmaf(h2.z, wh1[0], fmaf(h2.w, wh1[1], s1[2]));
            s0[3] = fmaf(h3.w, wh0[0], s0[3]);
            s1[3] = fmaf(h3.w, wh1[0], s1[3]);
        }

        // ---- butterfly reduce within the 16-lane group ----
#pragma unroll
        for (int m = 8; m >= 1; m >>= 1) {
#pragma unroll
            for (int i = 0; i < ROWS; ++i) {
                s0[i] += __shfl_xor(s0[i], m, 64);
                s1[i] += __shfl_xor(s1[i], m, 64);
            }
        }

        // ---- z broadcast (z0..z2 from lane 0's heads, z3 from lane 15 segB) ----
        float zz[ROWS];
        zz[0] = __shfl(z0, gbase, 64);
        zz[1] = __shfl(z1, gbase, 64);
        zz[2] = __shfl(z2, gbase, 64);
        zz[3] = __shfl(vb[3].w, gbase + 15, 64);   // row3 p=1: segB e3 = col 128

        // ---- f32 decision with conservative escalation test ----
        float oo[ROWS];
        bool esc = false;
#pragma unroll
        for (int i = 0; i < ROWS; ++i) {
            const float l0 = s0[i] + b0f;
            const float l1 = s1[i] + b1f;
            const float t  = (zz[i] == 1.0f) ? fmaxf(l0, l1) : fminf(l0, l1);
            const float qd = uu[i] * (1.0f + expf(-t));
            oo[i] = (qd < 1.0f) ? 1.0f : 0.0f;
            esc = esc || (fabsf(qd - 1.0f) < 2.5e-4f * (1.0f + qd));
        }

        // ---- rare exact f64 recompute (group-uniform branch; reloads x) ----
        if (__builtin_expect(esc, 0)) {
#pragma unroll 1
            for (int i = 0; i < ROWS; ++i) {
                const float* xr = x + (size_t)(r0 + i) * RS;
                double d0 = 0.0, d1 = 0.0;
#pragma unroll
                for (int j = 0; j < 8; ++j) {
                    const int c = 4 * sub + (j & 3) + 64 * (j >> 2);
                    const double xv = (double)xr[c];
                    d0 = fma(xv, (double)W[2 * c + 0], d0);
                    d1 = fma(xv, (double)W[2 * c + 1], d1);
                }
#pragma unroll
                for (int m = 8; m >= 1; m >>= 1) {
                    d0 += __shfl_xor(d0, m, 64);
                    d1 += __shfl_xor(d1, m, 64);
                }
                const double l0 = d0 + (double)b0f;
                const double l1 = d1 + (double)b1f;
                const double t  = (zz[i] == 1.0f) ? fmax(l0, l1) : fmin(l0, l1);
                oo[i] = ((double)uu[i] * (1.0 + exp(-t)) < 1.0) ? 1.0f : 0.0f;
            }
        }

        if (sub == 0) {
            *reinterpret_cast<float4*>(out + r0) =
                make_float4(oo[0], oo[1], oo[2], oo[3]);
        }
    }
}

extern "C" void kernel_launch(void* const* d_in, const int* in_sizes, int n_in,
                              void* d_out, int out_size, void* d_ws, size_t ws_size,
                              hipStream_t stream) {
    const float* x = (const float*)d_in[0];
    const float* W = (const float*)d_in[1];
    const float* b = (const float*)d_in[2];
    const float* u = (const float*)d_in[3];
    float* out = (float*)d_out;
    const int N = in_sizes[3];   // u has N elements

    const int blocks = 4096;     // grid-stride; 256 thr = 16 groups/block
    mono_kernel<<<blocks, 256, 0, stream>>>(x, W, b, u, out, N);
}

// Round 9
// 97.811 us; speedup vs baseline: 1.5385x; 1.0553x over previous
//
#include <hip/hip_runtime.h>
#include <math.h>

// monotonic_binary_output: out[r] = (u[r] < sigmoid-thresh[r]).
//
// v9 = v6 (best: 95.1 us) + non-temporal hints on the streaming traffic.
//  - x is 516 MB read exactly once: every cache fill is dead. nt loads
//    deprioritize L1/L2 allocation -> less fill/evict overhead on the
//    stream. out store and u load also nt.
//  - loads are bit-identical to v6 (same addresses, same dwordx4), so
//    numerics are unchanged: f32 hot path + rare f64 escape, decisions
//    identical to the pure-f64 kernel (absmax == 0.0, R1-R8).

constexpr int LATENT = 128;
constexpr int RS     = 129;          // x row stride in floats
constexpr int LPR    = 16;           // lanes cooperating per row
constexpr int CPL    = 8;            // cols per lane
constexpr int ROWS   = 4;            // rows per group-iteration

// float4 with honest 4-byte alignment (row stride 516 B -> segments are
// only 4B-aligned); gfx950 still selects global_load_dwordx4.
typedef float f4u __attribute__((ext_vector_type(4), aligned(4)));

__device__ __forceinline__ f4u load_nt4(const float* p) {
    return __builtin_nontemporal_load(reinterpret_cast<const f4u*>(p));
}

__global__ __launch_bounds__(256, 2)
void mono_kernel(const float* __restrict__ x,
                 const float* __restrict__ W,
                 const float* __restrict__ b,
                 const float* __restrict__ u,
                 float* __restrict__ out,
                 int N)
{
    const int tid  = blockIdx.x * blockDim.x + threadIdx.x;
    const int sub  = threadIdx.x & (LPR - 1);
    const int grp  = tid >> 4;
    const int ngrp = (gridDim.x * blockDim.x) >> 4;

    // Lane's column set: c(j) = 4*sub + (j&3) + 64*(j>>2), j = 0..7.
    float w0f[CPL], w1f[CPL];
#pragma unroll
    for (int j = 0; j < CPL; ++j) {
        const int c = 4 * sub + (j & 3) + 64 * (j >> 2);
        w0f[j] = W[2 * c + 0];
        w1f[j] = W[2 * c + 1];
    }
    const float b0f = b[0];
    const float b1f = b[1];

    const int nquad = N >> 2;                    // N = 1e6, divisible by 4
    for (int g = grp; g < nquad; g += ngrp) {
        const int r0 = 4 * g;

        // ---- loads: two nt dwordx4 per row per lane + z + u ----
        f4u va[ROWS], vb[ROWS];
        float zz[ROWS];
#pragma unroll
        for (int i = 0; i < ROWS; ++i) {
            const float* xr = x + (size_t)(r0 + i) * RS;
            va[i] = load_nt4(xr + 4 * sub);          // floats [4s, 4s+3]
            vb[i] = load_nt4(xr + 64 + 4 * sub);     // floats [64+4s, +3]
            zz[i] = __builtin_nontemporal_load(xr + LATENT);
        }
        const f4u uv = __builtin_nontemporal_load(
            reinterpret_cast<const f4u*>(u + r0));   // u + r0 is 16B-aligned
        const float uu[ROWS] = {uv.x, uv.y, uv.z, uv.w};

        // ---- f32 dot: 8 independent FMA chains ----
        float s0[ROWS], s1[ROWS];
#pragma unroll
        for (int i = 0; i < ROWS; ++i) {
            const float fa[CPL] = {va[i].x, va[i].y, va[i].z, va[i].w,
                                   vb[i].x, vb[i].y, vb[i].z, vb[i].w};
            float a0 = 0.0f, a1 = 0.0f;
#pragma unroll
            for (int j = 0; j < CPL; ++j) {
                a0 = fmaf(fa[j], w0f[j], a0);
                a1 = fmaf(fa[j], w1f[j], a1);
            }
            s0[i] = a0; s1[i] = a1;
        }

        // ---- butterfly reduce within the 16-lane group ----
#pragma unroll
        for (int m = 8; m >= 1; m >>= 1) {
#pragma unroll
            for (int i = 0; i < ROWS; ++i) {
                s0[i] += __shfl_xor(s0[i], m, 64);
                s1[i] += __shfl_xor(s1[i], m, 64);
            }
        }

        // ---- f32 decision with conservative escalation test ----
        float oo[ROWS];
        bool esc = false;
#pragma unroll
        for (int i = 0; i < ROWS; ++i) {
            const float l0 = s0[i] + b0f;
            const float l1 = s1[i] + b1f;
            const float t  = (zz[i] == 1.0f) ? fmaxf(l0, l1) : fminf(l0, l1);
            const float q  = uu[i] * (1.0f + expf(-t));
            oo[i] = (q < 1.0f) ? 1.0f : 0.0f;
            esc = esc || (fabsf(q - 1.0f) < 2.5e-4f * (1.0f + q));
        }

        // ---- rare exact f64 recompute (group-uniform branch; reloads x) ----
        if (__builtin_expect(esc, 0)) {
#pragma unroll 1
            for (int i = 0; i < ROWS; ++i) {
                const float* xr = x + (size_t)(r0 + i) * RS;
                double d0 = 0.0, d1 = 0.0;
#pragma unroll
                for (int j = 0; j < CPL; ++j) {
                    const int c = 4 * sub + (j & 3) + 64 * (j >> 2);
                    const double xv = (double)xr[c];
                    d0 = fma(xv, (double)w0f[j], d0);
                    d1 = fma(xv, (double)w1f[j], d1);
                }
#pragma unroll
                for (int m = 8; m >= 1; m >>= 1) {
                    d0 += __shfl_xor(d0, m, 64);
                    d1 += __shfl_xor(d1, m, 64);
                }
                const double l0 = d0 + (double)b0f;
                const double l1 = d1 + (double)b1f;
                const double t  = (zz[i] == 1.0f) ? fmax(l0, l1) : fmin(l0, l1);
                oo[i] = ((double)uu[i] * (1.0 + exp(-t)) < 1.0) ? 1.0f : 0.0f;
            }
        }

        if (sub == 0) {
            const f4u ov = {oo[0], oo[1], oo[2], oo[3]};
            __builtin_nontemporal_store(ov, reinterpret_cast<f4u*>(out + r0));
        }
    }
}

extern "C" void kernel_launch(void* const* d_in, const int* in_sizes, int n_in,
                              void* d_out, int out_size, void* d_ws, size_t ws_size,
                              hipStream_t stream) {
    const float* x = (const float*)d_in[0];
    const float* W = (const float*)d_in[1];
    const float* b = (const float*)d_in[2];
    const float* u = (const float*)d_in[3];
    float* out = (float*)d_out;
    const int N = in_sizes[3];   // u has N elements

    const int blocks = 4096;     // grid-stride; 256 thr = 16 groups/block
    mono_kernel<<<blocks, 256, 0, stream>>>(x, W, b, u, out, N);
}

// Round 10
// 95.349 us; speedup vs baseline: 1.5783x; 1.0258x over previous
//
#include <hip/hip_runtime.h>
#include <math.h>

// monotonic_binary_output: out[r] = (u[r] < sigmoid-thresh[r]).
//
// FINAL = v6 (best across 9 rounds: 95.1 us, 5.51 TB/s = 87.5% of the
// measured 6.29 TB/s copy ceiling on the 524 MB stream).
//
// Ceiling evidence (6 structurally distinct maximal variants):
//   v3 scalar loads 98.6 | v4 DMA-dbuf 101.3 | v5 DMA-4deep 113.8 |
//   v6 (this) 95.1 | v8 aligned-phase-shift 103.2 | v9 v6+nt 97.8.
// Refuted levers: DMA staging (LDS-capped occupancy + wait serialization),
// 16B alignment (align-4 dwordx4 is free), nt cache hints (neutral),
// deeper pipelining, occupancy caps (spill at 128-VGPR: R1/R7).
//
//  - Each lane reads two dwordx4 row segments (forced via __builtin_memcpy;
//    4B-aligned is fine on gfx950), 16 lanes per row, 4 rows per group.
//  - f32 hot path + conservative f64 escape: escalate iff
//    |q-1| < 2.5e-4*(1+q), q = u*(1+exp(-t)) -- ~8x margin over the f32
//    error bound, so decisions are identical to the pure-f64 kernel
//    (absmax == 0.0 in every round R1-R9).

constexpr int LATENT = 128;
constexpr int RS     = 129;          // x row stride in floats
constexpr int LPR    = 16;           // lanes cooperating per row
constexpr int CPL    = 8;            // cols per lane
constexpr int ROWS   = 4;            // rows per group-iteration

__device__ __forceinline__ float4 load_f4(const float* p) {
    float4 v;
    __builtin_memcpy(&v, p, sizeof(float4));   // unaligned-safe 16B load
    return v;
}

__global__ __launch_bounds__(256, 2)
void mono_kernel(const float* __restrict__ x,
                 const float* __restrict__ W,
                 const float* __restrict__ b,
                 const float* __restrict__ u,
                 float* __restrict__ out,
                 int N)
{
    const int tid  = blockIdx.x * blockDim.x + threadIdx.x;
    const int sub  = threadIdx.x & (LPR - 1);
    const int grp  = tid >> 4;
    const int ngrp = (gridDim.x * blockDim.x) >> 4;

    // Lane's column set: c(j) = 4*sub + (j&3) + 64*(j>>2), j = 0..7.
    float w0f[CPL], w1f[CPL];
#pragma unroll
    for (int j = 0; j < CPL; ++j) {
        const int c = 4 * sub + (j & 3) + 64 * (j >> 2);
        w0f[j] = W[2 * c + 0];
        w1f[j] = W[2 * c + 1];
    }
    const float b0f = b[0];
    const float b1f = b[1];

    const int nquad = N >> 2;                    // N = 1e6, divisible by 4
    for (int g = grp; g < nquad; g += ngrp) {
        const int r0 = 4 * g;

        // ---- loads: two forced dwordx4 per row per lane + z + u ----
        float4 va[ROWS], vb[ROWS];
        float  zz[ROWS];
#pragma unroll
        for (int i = 0; i < ROWS; ++i) {
            const float* xr = x + (size_t)(r0 + i) * RS;
            va[i] = load_f4(xr + 4 * sub);          // floats [4s, 4s+3]
            vb[i] = load_f4(xr + 64 + 4 * sub);     // floats [64+4s, 64+4s+3]
            zz[i] = xr[LATENT];
        }
        const float4 uv = *reinterpret_cast<const float4*>(u + r0);
        const float uu[ROWS] = {uv.x, uv.y, uv.z, uv.w};

        // ---- f32 dot: 8 independent FMA chains ----
        float s0[ROWS], s1[ROWS];
#pragma unroll
        for (int i = 0; i < ROWS; ++i) {
            const float fa[CPL] = {va[i].x, va[i].y, va[i].z, va[i].w,
                                   vb[i].x, vb[i].y, vb[i].z, vb[i].w};
            float a0 = 0.0f, a1 = 0.0f;
#pragma unroll
            for (int j = 0; j < CPL; ++j) {
                a0 = fmaf(fa[j], w0f[j], a0);
                a1 = fmaf(fa[j], w1f[j], a1);
            }
            s0[i] = a0; s1[i] = a1;
        }

        // ---- butterfly reduce within the 16-lane group ----
#pragma unroll
        for (int m = 8; m >= 1; m >>= 1) {
#pragma unroll
            for (int i = 0; i < ROWS; ++i) {
                s0[i] += __shfl_xor(s0[i], m, 64);
                s1[i] += __shfl_xor(s1[i], m, 64);
            }
        }

        // ---- f32 decision with conservative escalation test ----
        float oo[ROWS];
        bool esc = false;
#pragma unroll
        for (int i = 0; i < ROWS; ++i) {
            const float l0 = s0[i] + b0f;
            const float l1 = s1[i] + b1f;
            const float t  = (zz[i] == 1.0f) ? fmaxf(l0, l1) : fminf(l0, l1);
            const float q  = uu[i] * (1.0f + expf(-t));
            oo[i] = (q < 1.0f) ? 1.0f : 0.0f;
            esc = esc || (fabsf(q - 1.0f) < 2.5e-4f * (1.0f + q));
        }

        // ---- rare exact f64 recompute (group-uniform branch; reloads x) ----
        if (__builtin_expect(esc, 0)) {
#pragma unroll 1
            for (int i = 0; i < ROWS; ++i) {
                const float* xr = x + (size_t)(r0 + i) * RS;
                double d0 = 0.0, d1 = 0.0;
#pragma unroll
                for (int j = 0; j < CPL; ++j) {
                    const int c = 4 * sub + (j & 3) + 64 * (j >> 2);
                    const double xv = (double)xr[c];
                    d0 = fma(xv, (double)w0f[j], d0);
                    d1 = fma(xv, (double)w1f[j], d1);
                }
#pragma unroll
                for (int m = 8; m >= 1; m >>= 1) {
                    d0 += __shfl_xor(d0, m, 64);
                    d1 += __shfl_xor(d1, m, 64);
                }
                const double l0 = d0 + (double)b0f;
                const double l1 = d1 + (double)b1f;
                const double t  = (zz[i] == 1.0f) ? fmax(l0, l1) : fmin(l0, l1);
                oo[i] = ((double)uu[i] * (1.0 + exp(-t)) < 1.0) ? 1.0f : 0.0f;
            }
        }

        if (sub == 0) {
            *reinterpret_cast<float4*>(out + r0) =
                make_float4(oo[0], oo[1], oo[2], oo[3]);
        }
    }
}

extern "C" void kernel_launch(void* const* d_in, const int* in_sizes, int n_in,
                              void* d_out, int out_size, void* d_ws, size_t ws_size,
                              hipStream_t stream) {
    const float* x = (const float*)d_in[0];
    const float* W = (const float*)d_in[1];
    const float* b = (const float*)d_in[2];
    const float* u = (const float*)d_in[3];
    float* out = (float*)d_out;
    const int N = in_sizes[3];   // u has N elements

    const int blocks = 4096;     // grid-stride; 256 thr = 16 groups/block
    mono_kernel<<<blocks, 256, 0, stream>>>(x, W, b, u, out, N);
}